// Round 18
// baseline (1024.865 us; speedup 1.0000x reference)
//
#include <hip/hip_runtime.h>
#include <math.h>

#define N_ROWS 32768
#define DIM 256
#define KCODES 8192

#define BM 128                    // rows per block
#define BN 128                    // codes per kt tile
#define NSLICE 8
#define SLICE_K 1024
#define NKT (SLICE_K / BN)        // 8
#define NDT 8                     // 256 / 32 (BK=32 f16)
#define NSTEP (NKT * NDT)         // 64
#define TAU 2e-3f

#define FAST_SQRT(x) __builtin_amdgcn_sqrtf(x)

// ws layout (float offsets)
#define WS_C2    0
#define WS_X2    8192
#define WS_BD    40960
#define WS_BI    73728
#define WS_L     106496
#define WS_FLAGL 139264
#define WS_AVGP  172032
#define WS_CNT   180224
#define WS_SCAL  188416      // 0=mse 1=sum p*logp 2=avg_entropy 3=pent 4=nsum
#define WS_FLAGN 188424

#define PF (NSLICE * N_ROWS)

typedef _Float16 f16x8 __attribute__((ext_vector_type(8)));
typedef float f32x4 __attribute__((ext_vector_type(4)));

__device__ __forceinline__ void gll16(const void* g, void* l) {
    __builtin_amdgcn_global_load_lds((const __attribute__((address_space(1))) void*)g,
                                     (__attribute__((address_space(3))) void*)l, 16, 0, 0);
}

// f32 -> f16 (RNE) single plane + fused row sum-of-squares
__global__ void split_k(const float* __restrict__ src, ushort* __restrict__ h,
                        float* __restrict__ norms) {
    int tid = threadIdx.x;
    int i = blockIdx.x * 256 + tid;          // 8 elems per thread
    const float4* s4 = (const float4*)src;
    float4 v0 = s4[2 * i], v1 = s4[2 * i + 1];
    float vv[8] = {v0.x, v0.y, v0.z, v0.w, v1.x, v1.y, v1.z, v1.w};
    float nrm = 0.f;
    uint w[4];
    #pragma unroll
    for (int p = 0; p < 4; ++p) {
        float a = vv[2*p], b = vv[2*p+1];
        nrm = fmaf(a, a, nrm); nrm = fmaf(b, b, nrm);
        _Float16 ha = (_Float16)a, hb = (_Float16)b;
        w[p] = (uint)__builtin_bit_cast(unsigned short, ha)
             | ((uint)__builtin_bit_cast(unsigned short, hb) << 16);
    }
    ((uint4*)h)[i] = make_uint4(w[0], w[1], w[2], w[3]);
    #pragma unroll
    for (int off = 16; off >= 1; off >>= 1) nrm += __shfl_xor(nrm, off);
    if ((tid & 31) == 0) norms[blockIdx.x * 8 + (tid >> 5)] = nrm;
}

__global__ void init_ncbe_k(const float* __restrict__ cbe, float* __restrict__ outNcbe) {
    int i = blockIdx.x * 256 + threadIdx.x;
    float4 v = ((const float4*)cbe)[i];
    v.x *= 0.99f; v.y *= 0.99f; v.z *= 0.99f; v.w *= 0.99f;
    ((float4*)outNcbe)[i] = v;
}

__device__ __forceinline__ void online_merge(float& b1, int& i1, float& b2, float& l, float& T,
                                             float nb1, int ni1, float nb2, float nl, float nT) {
    float m  = fminf(b1, nb1);
    float fa = __expf(m - b1);
    float fb = __expf(m - nb1);
    float L  = fa * l + fb * nl;
    float TT = fa * (T + (m - b1) * l) + fb * (nT + (m - nb1) * nl);
    float losing = fmaxf(b1, nb1);
    float B2 = fminf(fminf(b2, nb2), losing);
    if (nb1 < b1 || (nb1 == b1 && ni1 < i1)) i1 = ni1;
    b1 = m; b2 = B2; l = L; T = TT;
}

// PASS 1: per-slice argmin (+2nd, packed 4-bit cand) + online softmax partials.
// PASS 2: avg_probs for own slice.
// LDS buf/step (bytes): cb[0,8192) x[8192,16384); f16 [128 rows][64B], chunk c at c^((row>>1)&3).
template<int PASS>
__global__ __launch_bounds__(512, 4) void vq_mfma(const ushort* __restrict__ xf,
                                                  const ushort* __restrict__ cf,
                                                  float* __restrict__ ws,
                                                  float* __restrict__ P) {
    __shared__ __align__(16) char lds[2][16384];   // 32 KB double buffer
    __shared__ __align__(16) float c2s[SLICE_K];   // 4 KB
    __shared__ float sred[1536];                   // 6 KB  -> total 43 KB => 3 blocks/CU

    const int tid  = threadIdx.x;
    const int lane = tid & 63, wid = tid >> 6;
    const int wcode = wid & 1, wx = wid >> 1;      // 2 code-groups(64) x 4 row-groups(32)
    const int l15 = lane & 15, l4 = lane >> 4;
    const int slice = blockIdx.x & 7, chunk = blockIdx.x >> 3;
    const int rowBase = chunk * BM;

    c2s[tid]       = ws[WS_C2 + slice * SLICE_K + tid];
    c2s[tid + 512] = ws[WS_C2 + slice * SLICE_K + tid + 512];
    if (PASS == 2) { sred[tid] = 0.f; sred[tid + 512] = 0.f; }

    // staging: 1024 16B chunks/step, 2/thread (1 cb + 1 x); LDS dst linear, source pre-swizzled
    const char* cbB; const char* xB; int dCB, dX;
    {
        int row = tid >> 2, c = tid & 3;
        int col = c ^ ((row >> 1) & 3);
        cbB = (const char*)cf + (((size_t)(slice * SLICE_K + row)) << 9) + (col << 4);
        xB  = (const char*)xf + (((size_t)(rowBase + row)) << 9) + (col << 4);
        dCB = tid << 4;
        dX  = 8192 + (tid << 4);
    }

    float x2v[2], bdv[2], invl[2];
    #pragma unroll
    for (int n = 0; n < 2; ++n) {
        int rl = wx * 32 + n * 16 + l15;
        x2v[n] = ws[WS_X2 + rowBase + rl];
        if (PASS == 2) {
            bdv[n]  = ws[WS_BD + rowBase + rl];
            invl[n] = 1.0f / ws[WS_L + rowBase + rl];
        }
    }
    float rb1[2], rb2[2], rlv[2], rTv[2]; int ri1[2];
    #pragma unroll
    for (int n = 0; n < 2; ++n) { rb1[n] = 1e30f; rb2[n] = 1e30f; rlv[n] = 0.f; rTv[n] = 0.f; ri1[n] = 0; }

    // prologue: stage t=0 into buf0
    gll16(cbB, &lds[0][dCB]);
    gll16(xB,  &lds[0][dX]);

    // read offsets: p = l4 ^ ((l15>>1)&3) constant per lane
    const int p = l4 ^ ((l15 >> 1) & 3);
    const int a0 = (wcode * 64 + l15) * 64 + p * 16;          // + m*1024
    const int b0 = 8192 + (wx * 32 + l15) * 64 + p * 16;      // + n*1024

    for (int kt = 0; kt < NKT; ++kt) {
        f32x4 acc[4][2];
        #pragma unroll
        for (int m = 0; m < 4; ++m) {
            acc[m][0] = (f32x4){0.f, 0.f, 0.f, 0.f};
            acc[m][1] = (f32x4){0.f, 0.f, 0.f, 0.f};
        }

        #pragma unroll
        for (int dt = 0; dt < NDT; ++dt) {
            const int t = kt * 8 + dt;
            if (t + 1 < NSTEP) {
                const int t1 = t + 1;
                const int cbo = ((t1 >> 3) << 16) | ((t1 & 7) << 6);
                const int xo  = (t1 & 7) << 6;
                char* wb = &lds[t1 & 1][0];
                gll16(cbB + cbo, wb + dCB);
                gll16(xB + xo,   wb + dX);
                asm volatile("s_waitcnt vmcnt(2)" ::: "memory");   // stage(t) landed
            } else {
                asm volatile("s_waitcnt vmcnt(0)" ::: "memory");
            }
            __builtin_amdgcn_s_barrier();
            __builtin_amdgcn_sched_barrier(0);

            const char* bb = &lds[t & 1][0];
            f16x8 Bf[2];
            #pragma unroll
            for (int n = 0; n < 2; ++n)
                Bf[n] = __builtin_bit_cast(f16x8, *(const uint4*)(bb + b0 + n * 1024));
            __builtin_amdgcn_s_setprio(1);
            #pragma unroll
            for (int m = 0; m < 4; ++m) {
                f16x8 Af = __builtin_bit_cast(f16x8, *(const uint4*)(bb + a0 + m * 1024));
                acc[m][0] = __builtin_amdgcn_mfma_f32_16x16x32_f16(Af, Bf[0], acc[m][0], 0, 0, 0);
                acc[m][1] = __builtin_amdgcn_mfma_f32_16x16x32_f16(Af, Bf[1], acc[m][1], 0, 0, 0);
            }
            __builtin_amdgcn_s_setprio(0);
            __builtin_amdgcn_sched_barrier(0);
            __builtin_amdgcn_s_barrier();
        }

        // epilogue: lane holds D[code=(l4*4+r)+16m][xrow=l15+16n]; no vmem.
        // Packed (dv,cand4) argmin: top-28 bits dv (quantum ~3e-5), low-4 bits cand=m*4+r.
        const int lcb = kt * BN + wcode * 64 + l4 * 4;   // in-slice code base
        if (PASS == 1) {
            #pragma unroll
            for (int n = 0; n < 2; ++n) {
                uint pm = ~0u, p2 = ~0u;
                float dsv[16];
                #pragma unroll
                for (int m = 0; m < 4; ++m) {
                    float4 c2v = *(const float4*)&c2s[lcb + m * 16];
                    #pragma unroll
                    for (int r = 0; r < 4; ++r) {
                        float d2 = fmaf(-2.f, acc[m][n][r], x2v[n] + ((const float*)&c2v)[r]);
                        float dv = FAST_SQRT(fmaxf(d2, 0.f));
                        dsv[m * 4 + r] = dv;
                        uint pk = (__float_as_uint(dv) & 0xFFFFFFF0u) | (uint)(m * 4 + r);
                        bool lt = pk < pm;
                        uint alt = (pk < p2) ? pk : p2;
                        p2 = lt ? pm : alt;
                        pm = lt ? pk : pm;
                    }
                }
                uint cand = pm & 15u;
                float b1  = __uint_as_float(pm & 0xFFFFFFF0u);
                float b2v = __uint_as_float(p2 & 0xFFFFFFF0u);
                int   i1  = slice * SLICE_K + lcb + (int)((cand >> 2) << 4) + (int)(cand & 3u);
                float ls = 0.f, ts = 0.f;
                #pragma unroll
                for (int q = 0; q < 16; ++q) {
                    float u = b1 - dsv[q];
                    float e = __expf(u);
                    ls += e;
                    ts = fmaf(e, u, ts);
                }
                online_merge(rb1[n], ri1[n], rb2[n], rlv[n], rTv[n], b1, i1, b2v, ls, ts);
            }
        } else {
            float ps[4][4];
            #pragma unroll
            for (int m = 0; m < 4; ++m)
                #pragma unroll
                for (int r = 0; r < 4; ++r) ps[m][r] = 0.f;
            #pragma unroll
            for (int n = 0; n < 2; ++n) {
                #pragma unroll
                for (int m = 0; m < 4; ++m) {
                    float4 c2v = *(const float4*)&c2s[lcb + m * 16];
                    #pragma unroll
                    for (int r = 0; r < 4; ++r) {
                        float d2 = fmaf(-2.f, acc[m][n][r], x2v[n] + ((const float*)&c2v)[r]);
                        float dv = FAST_SQRT(fmaxf(d2, 0.f));
                        ps[m][r] = fmaf(__expf(bdv[n] - dv), invl[n], ps[m][r]);
                    }
                }
            }
            #pragma unroll
            for (int m = 0; m < 4; ++m)
                #pragma unroll
                for (int r = 0; r < 4; ++r) {
                    float v = ps[m][r];
                    v += __shfl_xor(v, 1); v += __shfl_xor(v, 2);
                    v += __shfl_xor(v, 4); v += __shfl_xor(v, 8);
                    ps[m][r] = v;
                }
            if (l15 == 0) {
                #pragma unroll
                for (int m = 0; m < 4; ++m)
                    #pragma unroll
                    for (int r = 0; r < 4; ++r)
                        atomicAdd(&sred[lcb + m * 16 + r], ps[m][r]);
            }
        }
    }

    if (PASS == 1) {
        #pragma unroll
        for (int n = 0; n < 2; ++n) {
            #pragma unroll
            for (int off = 16; off <= 32; off <<= 1) {
                float ob1 = __shfl_xor(rb1[n], off);
                int   oi  = __shfl_xor(ri1[n], off);
                float ob2 = __shfl_xor(rb2[n], off);
                float ol  = __shfl_xor(rlv[n], off);
                float oT  = __shfl_xor(rTv[n], off);
                online_merge(rb1[n], ri1[n], rb2[n], rlv[n], rTv[n], ob1, oi, ob2, ol, oT);
            }
        }
        if (l4 == 0) {
            #pragma unroll
            for (int n = 0; n < 2; ++n) {
                int rl = wx * 32 + n * 16 + l15;
                sred[(rl << 1) + wcode]       = rb1[n];
                sred[256 + (rl << 1) + wcode] = rb2[n];
                sred[512 + (rl << 1) + wcode] = rlv[n];
                sred[768 + (rl << 1) + wcode] = rTv[n];
                ((int*)sred)[1024 + (rl << 1) + wcode] = ri1[n];
            }
        }
        __syncthreads();
        if (tid < BM) {
            float b1 = sred[tid * 2];       int i1 = ((int*)sred)[1024 + tid * 2];
            float b2 = sred[256 + tid * 2];
            float L  = sred[512 + tid * 2];
            float T  = sred[768 + tid * 2];
            online_merge(b1, i1, b2, L, T,
                         sred[tid * 2 + 1], ((int*)sred)[1024 + tid * 2 + 1],
                         sred[256 + tid * 2 + 1], sred[512 + tid * 2 + 1], sred[768 + tid * 2 + 1]);
            int grow = rowBase + tid;
            P[0 * PF + slice * N_ROWS + grow] = b1;
            P[1 * PF + slice * N_ROWS + grow] = b2;
            P[2 * PF + slice * N_ROWS + grow] = L;
            P[3 * PF + slice * N_ROWS + grow] = T;
            ((int*)P)[4 * PF + slice * N_ROWS + grow] = i1;
        }
    } else {
        __syncthreads();
        atomicAdd(&ws[WS_AVGP + slice * SLICE_K + tid], sred[tid]);
        atomicAdd(&ws[WS_AVGP + slice * SLICE_K + tid + 512], sred[tid + 512]);
    }
}

// merge 8 slice-partials per row -> final stats + flags (enc init) + entropy sum
__global__ void merge_k(const float* __restrict__ P, float* __restrict__ ws,
                        unsigned long long* __restrict__ enc) {
    const int tid = threadIdx.x, lane = tid & 63;
    const int row = blockIdx.x * 256 + tid;
    float b1 = 1e30f, b2 = 1e30f, L = 0.f, T = 0.f; int i1 = 0;
    #pragma unroll
    for (int s = 0; s < NSLICE; ++s) {
        float nb1 = P[0 * PF + s * N_ROWS + row];
        float nb2 = P[1 * PF + s * N_ROWS + row];
        float nl  = P[2 * PF + s * N_ROWS + row];
        float nT  = P[3 * PF + s * N_ROWS + row];
        int   ni  = ((const int*)P)[4 * PF + s * N_ROWS + row];
        online_merge(b1, i1, b2, L, T, nb1, ni, nb2, nl, nT);
    }
    ws[WS_BD + row] = b1;
    ((int*)ws)[WS_BI + row] = i1;
    ws[WS_L + row] = L;
    if (b2 - b1 < TAU) {
        int p = atomicAdd(((int*)ws) + WS_FLAGN, 1);
        ((int*)ws)[WS_FLAGL + p] = row;
        enc[p] = ~0ULL;
    }
    float sval = T / L - __logf(L);
    #pragma unroll
    for (int off = 32; off >= 1; off >>= 1) sval += __shfl_xor(sval, off);
    if (lane == 0) atomicAdd(&ws[WS_SCAL + 1], sval);
}

// exact f32 argmin: grid = 8 slices x 256 row-groups; block grid-strides flagged rows.
// 16-lane groups: 4 codes per wave-iter; x-row in registers; no barriers in row loop.
__global__ __launch_bounds__(256) void fixup_k(const float* __restrict__ x,
                                               const float* __restrict__ cb,
                                               float* __restrict__ ws,
                                               unsigned long long* __restrict__ enc) {
    __shared__ __align__(16) float c2sl[SLICE_K];
    const int tid = threadIdx.x, lane = tid & 63, wid = tid >> 6;
    const int g = lane >> 4, l15 = lane & 15;
    const int slice = blockIdx.x & 7;
    for (int i = tid; i < SLICE_K; i += 256) c2sl[i] = ws[WS_C2 + slice * SLICE_K + i];
    __syncthreads();
    const int nf = ((const int*)ws)[WS_FLAGN];
    const int cbase = slice * SLICE_K + wid * 256;     // this wave's 256-code range
    for (int fi = blockIdx.x >> 3; fi < nf; fi += (gridDim.x >> 3)) {
        const int row = ((const int*)ws)[WS_FLAGL + fi];
        const float4* xp = (const float4*)(x + (size_t)row * DIM) + l15 * 4;
        float4 xr0 = xp[0], xr1 = xp[1], xr2 = xp[2], xr3 = xp[3];
        const float x2r = ws[WS_X2 + row];
        unsigned long long best = ~0ULL;
        #pragma unroll 4
        for (int j = 0; j < 64; ++j) {
            const int c = cbase + j * 4 + g;
            const float4* cp = (const float4*)(cb + (size_t)c * DIM) + l15 * 4;
            float4 c0 = cp[0], c1 = cp[1], c2 = cp[2], c3 = cp[3];
            float dot = c0.x * xr0.x;
            dot = fmaf(c0.y, xr0.y, dot); dot = fmaf(c0.z, xr0.z, dot); dot = fmaf(c0.w, xr0.w, dot);
            dot = fmaf(c1.x, xr1.x, dot); dot = fmaf(c1.y, xr1.y, dot);
            dot = fmaf(c1.z, xr1.z, dot); dot = fmaf(c1.w, xr1.w, dot);
            dot = fmaf(c2.x, xr2.x, dot); dot = fmaf(c2.y, xr2.y, dot);
            dot = fmaf(c2.z, xr2.z, dot); dot = fmaf(c2.w, xr2.w, dot);
            dot = fmaf(c3.x, xr3.x, dot); dot = fmaf(c3.y, xr3.y, dot);
            dot = fmaf(c3.z, xr3.z, dot); dot = fmaf(c3.w, xr3.w, dot);
            dot += __shfl_xor(dot, 1); dot += __shfl_xor(dot, 2);
            dot += __shfl_xor(dot, 4); dot += __shfl_xor(dot, 8);
            float d2 = fmaxf(fmaf(-2.f, dot, x2r + c2sl[wid * 256 + j * 4 + g]), 0.f);
            float dv = sqrtf(d2);
            unsigned long long e = (((unsigned long long)__float_as_uint(dv)) << 32)
                                 | (unsigned int)c;
            best = (e < best) ? e : best;
        }
        {
            unsigned long long o = __shfl_xor(best, 16);
            best = (o < best) ? o : best;
            o = __shfl_xor(best, 32);
            best = (o < best) ? o : best;
        }
        if (lane == 0) atomicMin(&enc[fi], best);
    }
}

__global__ void unpack_k(const unsigned long long* __restrict__ enc, float* __restrict__ ws) {
    int f = blockIdx.x * 256 + threadIdx.x;
    int nf = ((const int*)ws)[WS_FLAGN];
    if (f < nf) {
        int row = ((const int*)ws)[WS_FLAGL + f];
        ((int*)ws)[WS_BI + row] = (int)(enc[f] & 0xFFFFFFFFu);
    }
}

__global__ void gather_k(const float* __restrict__ x, const float* __restrict__ cb,
                         float* __restrict__ ws, float* __restrict__ outQ,
                         float* __restrict__ outNcbe, float* __restrict__ outIdxF) {
    __shared__ float red2[4];
    const int tid = threadIdx.x, w = tid >> 6, lane = tid & 63;
    float msum = 0.f;
    for (int it = 0; it < 8; ++it) {
        int n = blockIdx.x * 32 + it * 4 + w;
        int idx = ((const int*)ws)[WS_BI + n];
        float4 xv = ((const float4*)(x + (size_t)n * DIM))[lane];
        float4 cv = ((const float4*)(cb + (size_t)idx * DIM))[lane];
        ((float4*)(outQ + (size_t)n * DIM))[lane] = cv;
        float* dst = outNcbe + (size_t)idx * DIM + lane * 4;
        const float g = 0.01f;
        atomicAdd(dst + 0, g * xv.x); atomicAdd(dst + 1, g * xv.y);
        atomicAdd(dst + 2, g * xv.z); atomicAdd(dst + 3, g * xv.w);
        float dx = cv.x - xv.x, dy = cv.y - xv.y, dz = cv.z - xv.z, dw = cv.w - xv.w;
        float s = dx*dx + dy*dy + dz*dz + dw*dw;
        #pragma unroll
        for (int off = 32; off >= 1; off >>= 1) s += __shfl_xor(s, off);
        if (lane == 0) {
            msum += s;
            atomicAdd(&ws[WS_CNT + idx], 1.0f);
            outIdxF[n] = (float)idx;
        }
    }
    if (lane == 0) red2[w] = msum;
    __syncthreads();
    if (tid == 0) atomicAdd(&ws[WS_SCAL + 0], red2[0] + red2[1] + red2[2] + red2[3]);
}

__global__ void stats_k(const float* __restrict__ cse, float* __restrict__ ws,
                        float* __restrict__ outNcse) {
    int tid = threadIdx.x, lane = tid & 63;
    int k = blockIdx.x * 256 + tid;
    float cnt = ws[WS_CNT + k];
    float ncse = 0.99f * cse[k] + 0.01f * cnt;
    outNcse[k] = ncse;
    float ap  = ws[WS_AVGP + k] * (1.0f / N_ROWS);
    float ae  = -(ap * __logf(ap + 1e-5f));
    float app = cnt * (1.0f / N_ROWS);
    float pe  = -(app * __logf(app + 1e-10f));
    #pragma unroll
    for (int off = 32; off >= 1; off >>= 1) {
        ncse += __shfl_xor(ncse, off);
        ae   += __shfl_xor(ae, off);
        pe   += __shfl_xor(pe, off);
    }
    if (lane == 0) {
        atomicAdd(&ws[WS_SCAL + 4], ncse);
        atomicAdd(&ws[WS_SCAL + 2], ae);
        atomicAdd(&ws[WS_SCAL + 3], pe);
    }
}

__global__ void newcb_k(const float* __restrict__ ws, const float* __restrict__ outNcse,
                        const float* __restrict__ outNcbe, float* __restrict__ outNc) {
    int w = threadIdx.x >> 6, lane = threadIdx.x & 63;
    int k = blockIdx.x * 4 + w;
    float n = ws[WS_SCAL + 4];
    float ncse = outNcse[k];
    float smoothed = (ncse + 1e-5f) / (n + (float)KCODES * 1e-5f) * n;
    float inv = 1.0f / smoothed;
    float4 v = ((const float4*)(outNcbe + (size_t)k * DIM))[lane];
    v.x *= inv; v.y *= inv; v.z *= inv; v.w *= inv;
    ((float4*)(outNc + (size_t)k * DIM))[lane] = v;
}

__global__ void finalize_k(const float* __restrict__ ws, float* __restrict__ outLoss,
                           float* __restrict__ outPerp) {
    float mse  = ws[WS_SCAL + 0] * (1.0f / ((float)N_ROWS * 256.0f));
    float sent = -ws[WS_SCAL + 1] * (1.0f / (float)N_ROWS);
    float ent  = sent - ws[WS_SCAL + 2];
    outLoss[0] = 1.25f * mse + 0.1f * ent;
    outPerp[0] = expf(ws[WS_SCAL + 3]);
}

extern "C" void kernel_launch(void* const* d_in, const int* in_sizes, int n_in,
                              void* d_out, int out_size, void* d_ws, size_t ws_size,
                              hipStream_t stream) {
    const float* x   = (const float*)d_in[0];
    const float* cb  = (const float*)d_in[1];
    const float* cse = (const float*)d_in[2];
    const float* cbe = (const float*)d_in[3];
    float* out = (float*)d_out;
    float* ws  = (float*)d_ws;

    float* outQ    = out;
    float* outLoss = out + 8388608;
    float* outPerp = out + 8388609;
    float* outIdxF = out + 8388610;
    float* outNc   = out + 8421378;
    float* outNcse = out + 10518530;
    float* outNcbe = out + 10526722;

    // scratch inside d_out: x f16 in outQ, cb f16 in outNc(+2 align), partials+enc in outNcbe
    ushort* xf = (ushort*)outQ;                    // 16 MB
    ushort* cf = (ushort*)(out + 8421380);         // 4 MB
    float*  P  = outNcbe;                          // 5.24 MB
    unsigned long long* enc = (unsigned long long*)(outNcbe + 5 * PF);  // 256 KB

    (void)hipMemsetAsync(ws + WS_AVGP, 0, (size_t)(WS_FLAGN + 1 - WS_AVGP) * sizeof(float), stream);
    split_k<<<N_ROWS * DIM / 2048, 256, 0, stream>>>(x, xf, ws + WS_X2);
    split_k<<<KCODES * DIM / 2048, 256, 0, stream>>>(cb, cf, ws + WS_C2);
    vq_mfma<1><<<NSLICE * (N_ROWS / BM), 512, 0, stream>>>(xf, cf, ws, P);
    merge_k<<<N_ROWS / 256, 256, 0, stream>>>(P, ws, enc);
    vq_mfma<2><<<NSLICE * (N_ROWS / BM), 512, 0, stream>>>(xf, cf, ws, P);
    fixup_k<<<2048, 256, 0, stream>>>(x, cb, ws, enc);
    unpack_k<<<N_ROWS / 256, 256, 0, stream>>>(enc, ws);
    init_ncbe_k<<<2048, 256, 0, stream>>>(cbe, outNcbe);
    gather_k<<<1024, 256, 0, stream>>>(x, cb, ws, outQ, outNcbe, outIdxF);
    stats_k<<<KCODES / 256, 256, 0, stream>>>(cse, ws, outNcse);
    newcb_k<<<KCODES / 4, 256, 0, stream>>>(ws, outNcse, outNcbe, outNc);
    finalize_k<<<1, 1, 0, stream>>>(ws, outLoss, outPerp);
}

// Round 19
// 871.555 us; speedup vs baseline: 1.1759x; 1.1759x over previous
//
#include <hip/hip_runtime.h>
#include <math.h>

#define N_ROWS 32768
#define DIM 256
#define KCODES 8192

#define BM 128                    // rows per block
#define BN 128                    // codes per kt tile
#define NSLICE 8
#define SLICE_K 1024
#define NKT (SLICE_K / BN)        // 8
#define NDT 4                     // 256 / 64 (BK=64 f16)
#define NSTEP (NKT * NDT)         // 32
#define TAU 2e-3f
#define EPS2 4e-3f                // 2 * approx-error bound for slice pruning

#define FAST_SQRT(x) __builtin_amdgcn_sqrtf(x)

// ws layout (float offsets)
#define WS_C2    0
#define WS_X2    8192
#define WS_BD    40960
#define WS_BI    73728
#define WS_L     106496
#define WS_FLAGL 139264
#define WS_AVGP  172032
#define WS_CNT   180224
#define WS_SCAL  188416      // 0=mse 1=sum p*logp 2=avg_entropy 3=pent 4=nsum
#define WS_FLAGN 188424

#define PF (NSLICE * N_ROWS)

typedef _Float16 f16x8 __attribute__((ext_vector_type(8)));
typedef float f32x4 __attribute__((ext_vector_type(4)));

__device__ __forceinline__ void gll16(const void* g, void* l) {
    __builtin_amdgcn_global_load_lds((const __attribute__((address_space(1))) void*)g,
                                     (__attribute__((address_space(3))) void*)l, 16, 0, 0);
}

// f32 -> f16 (RNE) single plane + fused row sum-of-squares
__global__ void split_k(const float* __restrict__ src, ushort* __restrict__ h,
                        float* __restrict__ norms) {
    int tid = threadIdx.x;
    int i = blockIdx.x * 256 + tid;          // 8 elems per thread
    const float4* s4 = (const float4*)src;
    float4 v0 = s4[2 * i], v1 = s4[2 * i + 1];
    float vv[8] = {v0.x, v0.y, v0.z, v0.w, v1.x, v1.y, v1.z, v1.w};
    float nrm = 0.f;
    uint w[4];
    #pragma unroll
    for (int p = 0; p < 4; ++p) {
        float a = vv[2*p], b = vv[2*p+1];
        nrm = fmaf(a, a, nrm); nrm = fmaf(b, b, nrm);
        _Float16 ha = (_Float16)a, hb = (_Float16)b;
        w[p] = (uint)__builtin_bit_cast(unsigned short, ha)
             | ((uint)__builtin_bit_cast(unsigned short, hb) << 16);
    }
    ((uint4*)h)[i] = make_uint4(w[0], w[1], w[2], w[3]);
    #pragma unroll
    for (int off = 16; off >= 1; off >>= 1) nrm += __shfl_xor(nrm, off);
    if ((tid & 31) == 0) norms[blockIdx.x * 8 + (tid >> 5)] = nrm;
}

__global__ void init_ncbe_k(const float* __restrict__ cbe, float* __restrict__ outNcbe) {
    int i = blockIdx.x * 256 + threadIdx.x;
    float4 v = ((const float4*)cbe)[i];
    v.x *= 0.99f; v.y *= 0.99f; v.z *= 0.99f; v.w *= 0.99f;
    ((float4*)outNcbe)[i] = v;
}

__device__ __forceinline__ void online_merge(float& b1, int& i1, float& b2, float& l, float& T,
                                             float nb1, int ni1, float nb2, float nl, float nT) {
    float m  = fminf(b1, nb1);
    float fa = __expf(m - b1);
    float fb = __expf(m - nb1);
    float L  = fa * l + fb * nl;
    float TT = fa * (T + (m - b1) * l) + fb * (nT + (m - nb1) * nl);
    float losing = fmaxf(b1, nb1);
    float B2 = fminf(fminf(b2, nb2), losing);
    if (nb1 < b1 || (nb1 == b1 && ni1 < i1)) i1 = ni1;
    b1 = m; b2 = B2; l = L; T = TT;
}

// PASS 1: per-slice argmin (+2nd, packed 4-bit cand) + online softmax partials.
// PASS 2: avg_probs for own slice.
// LDS buf (bytes): cb[0,16K) x[16K,32K); f16 tiles [128 rows][128B], chunk c at slot c^(row&7).
template<int PASS>
__global__ __launch_bounds__(512, 4) void vq_mfma(const ushort* __restrict__ xf,
                                                  const ushort* __restrict__ cf,
                                                  float* __restrict__ ws,
                                                  float* __restrict__ P) {
    __shared__ __align__(16) char lds[2][32768];   // 64 KB double buffer
    __shared__ __align__(16) float c2s[SLICE_K];   // 4 KB
    __shared__ float sred[1536];                   // 6 KB

    const int tid  = threadIdx.x;
    const int lane = tid & 63, wid = tid >> 6;
    const int wcode = wid & 1, wx = wid >> 1;      // 2 code-groups(64) x 4 row-groups(32)
    const int l15 = lane & 15, l4 = lane >> 4;
    const int slice = blockIdx.x & 7, chunk = blockIdx.x >> 3;
    const int rowBase = chunk * BM;

    c2s[tid]       = ws[WS_C2 + slice * SLICE_K + tid];
    c2s[tid + 512] = ws[WS_C2 + slice * SLICE_K + tid + 512];
    if (PASS == 2) { sred[tid] = 0.f; sred[tid + 512] = 0.f; }

    // staging: 2048 16B chunks/step, 4 per thread (2 cb + 2 x); LDS dst = wave-uniform + lane*16
    const char* cbB[2]; const char* xB[2]; int dCB[2], dX[2];
    #pragma unroll
    for (int j = 0; j < 2; ++j) {
        int q = j * 512 + tid;
        int row = q >> 3, c = tid & 7;
        int sw = (c ^ (row & 7)) << 4;             // pre-swizzled global source
        cbB[j] = (const char*)cf + (((size_t)(slice * SLICE_K + row)) << 9) + sw;
        xB[j]  = (const char*)xf + (((size_t)(rowBase + row)) << 9) + sw;
        dCB[j] = q << 4;
        dX[j]  = 16384 + (q << 4);
    }

    float x2v[2], bdv[2], invl[2];
    #pragma unroll
    for (int n = 0; n < 2; ++n) {
        int rl = wx * 32 + n * 16 + l15;
        x2v[n] = ws[WS_X2 + rowBase + rl];
        if (PASS == 2) {
            bdv[n]  = ws[WS_BD + rowBase + rl];
            invl[n] = 1.0f / ws[WS_L + rowBase + rl];
        }
    }
    float rb1[2], rb2[2], rlv[2], rTv[2]; int ri1[2];
    #pragma unroll
    for (int n = 0; n < 2; ++n) { rb1[n] = 1e30f; rb2[n] = 1e30f; rlv[n] = 0.f; rTv[n] = 0.f; ri1[n] = 0; }

    // prologue: stage t=0 into buf0
    #pragma unroll
    for (int j = 0; j < 2; ++j) {
        gll16(cbB[j], &lds[0][dCB[j]]);
        gll16(xB[j],  &lds[0][dX[j]]);
    }

    const int swkey = l15 & 7;

    for (int kt = 0; kt < NKT; ++kt) {
        f32x4 acc[4][2];
        #pragma unroll
        for (int m = 0; m < 4; ++m) {
            acc[m][0] = (f32x4){0.f, 0.f, 0.f, 0.f};
            acc[m][1] = (f32x4){0.f, 0.f, 0.f, 0.f};
        }

        #pragma unroll
        for (int dt = 0; dt < NDT; ++dt) {
            const int t = kt * 4 + dt;
            if (t + 1 < NSTEP) {
                const int t1 = t + 1;
                const int cbo = ((t1 >> 2) << 16) | ((t1 & 3) << 7);
                const int xo  = (t1 & 3) << 7;
                char* wb = &lds[t1 & 1][0];
                #pragma unroll
                for (int j = 0; j < 2; ++j) {
                    gll16(cbB[j] + cbo, wb + dCB[j]);
                    gll16(xB[j] + xo,   wb + dX[j]);
                }
                asm volatile("s_waitcnt vmcnt(4)" ::: "memory");   // stage(t) landed
            } else {
                asm volatile("s_waitcnt vmcnt(0)" ::: "memory");
            }
            __builtin_amdgcn_s_barrier();
            __builtin_amdgcn_sched_barrier(0);

            const char* bb = &lds[t & 1][0];
            #pragma unroll
            for (int s = 0; s < 2; ++s) {
                const int csw = (((s << 2) | l4) ^ swkey) << 4;
                f16x8 Bf[2];
                #pragma unroll
                for (int n = 0; n < 2; ++n)
                    Bf[n] = __builtin_bit_cast(f16x8,
                        *(const uint4*)(bb + 16384 + (wx * 32 + n * 16 + l15) * 128 + csw));
                __builtin_amdgcn_s_setprio(1);
                #pragma unroll
                for (int m = 0; m < 4; ++m) {
                    f16x8 Af = __builtin_bit_cast(f16x8,
                        *(const uint4*)(bb + (wcode * 64 + m * 16 + l15) * 128 + csw));
                    acc[m][0] = __builtin_amdgcn_mfma_f32_16x16x32_f16(Af, Bf[0], acc[m][0], 0, 0, 0);
                    acc[m][1] = __builtin_amdgcn_mfma_f32_16x16x32_f16(Af, Bf[1], acc[m][1], 0, 0, 0);
                }
                __builtin_amdgcn_s_setprio(0);
            }
            __builtin_amdgcn_sched_barrier(0);
            __builtin_amdgcn_s_barrier();
        }

        // epilogue: lane holds D[code=(l4*4+r)+16m][xrow=l15+16n]; no vmem.
        // Packed (dv,cand4) argmin: top-28 bits dv (quantum ~3e-5), low-4 bits cand=m*4+r.
        const int lcb = kt * BN + wcode * 64 + l4 * 4;   // in-slice code base
        if (PASS == 1) {
            #pragma unroll
            for (int n = 0; n < 2; ++n) {
                uint pm = ~0u, p2 = ~0u;
                float dsv[16];
                #pragma unroll
                for (int m = 0; m < 4; ++m) {
                    float4 c2v = *(const float4*)&c2s[lcb + m * 16];
                    #pragma unroll
                    for (int r = 0; r < 4; ++r) {
                        float d2 = fmaf(-2.f, acc[m][n][r], x2v[n] + ((const float*)&c2v)[r]);
                        float dv = FAST_SQRT(fmaxf(d2, 0.f));
                        dsv[m * 4 + r] = dv;
                        uint pk = (__float_as_uint(dv) & 0xFFFFFFF0u) | (uint)(m * 4 + r);
                        bool lt = pk < pm;
                        uint alt = (pk < p2) ? pk : p2;
                        p2 = lt ? pm : alt;
                        pm = lt ? pk : pm;
                    }
                }
                uint cand = pm & 15u;
                float b1  = __uint_as_float(pm & 0xFFFFFFF0u);
                float b2v = __uint_as_float(p2 & 0xFFFFFFF0u);
                int   i1  = slice * SLICE_K + lcb + (int)((cand >> 2) << 4) + (int)(cand & 3u);
                float ls = 0.f, ts = 0.f;
                #pragma unroll
                for (int q = 0; q < 16; ++q) {
                    float u = b1 - dsv[q];
                    float e = __expf(u);
                    ls += e;
                    ts = fmaf(e, u, ts);
                }
                online_merge(rb1[n], ri1[n], rb2[n], rlv[n], rTv[n], b1, i1, b2v, ls, ts);
            }
        } else {
            float ps[4][4];
            #pragma unroll
            for (int m = 0; m < 4; ++m)
                #pragma unroll
                for (int r = 0; r < 4; ++r) ps[m][r] = 0.f;
            #pragma unroll
            for (int n = 0; n < 2; ++n) {
                #pragma unroll
                for (int m = 0; m < 4; ++m) {
                    float4 c2v = *(const float4*)&c2s[lcb + m * 16];
                    #pragma unroll
                    for (int r = 0; r < 4; ++r) {
                        float d2 = fmaf(-2.f, acc[m][n][r], x2v[n] + ((const float*)&c2v)[r]);
                        float dv = FAST_SQRT(fmaxf(d2, 0.f));
                        ps[m][r] = fmaf(__expf(bdv[n] - dv), invl[n], ps[m][r]);
                    }
                }
            }
            #pragma unroll
            for (int m = 0; m < 4; ++m)
                #pragma unroll
                for (int r = 0; r < 4; ++r) {
                    float v = ps[m][r];
                    v += __shfl_xor(v, 1); v += __shfl_xor(v, 2);
                    v += __shfl_xor(v, 4); v += __shfl_xor(v, 8);
                    ps[m][r] = v;
                }
            if (l15 == 0) {
                #pragma unroll
                for (int m = 0; m < 4; ++m)
                    #pragma unroll
                    for (int r = 0; r < 4; ++r)
                        atomicAdd(&sred[lcb + m * 16 + r], ps[m][r]);
            }
        }
    }

    if (PASS == 1) {
        #pragma unroll
        for (int n = 0; n < 2; ++n) {
            #pragma unroll
            for (int off = 16; off <= 32; off <<= 1) {
                float ob1 = __shfl_xor(rb1[n], off);
                int   oi  = __shfl_xor(ri1[n], off);
                float ob2 = __shfl_xor(rb2[n], off);
                float ol  = __shfl_xor(rlv[n], off);
                float oT  = __shfl_xor(rTv[n], off);
                online_merge(rb1[n], ri1[n], rb2[n], rlv[n], rTv[n], ob1, oi, ob2, ol, oT);
            }
        }
        if (l4 == 0) {
            #pragma unroll
            for (int n = 0; n < 2; ++n) {
                int rl = wx * 32 + n * 16 + l15;
                sred[(rl << 1) + wcode]       = rb1[n];
                sred[256 + (rl << 1) + wcode] = rb2[n];
                sred[512 + (rl << 1) + wcode] = rlv[n];
                sred[768 + (rl << 1) + wcode] = rTv[n];
                ((int*)sred)[1024 + (rl << 1) + wcode] = ri1[n];
            }
        }
        __syncthreads();
        if (tid < BM) {
            float b1 = sred[tid * 2];       int i1 = ((int*)sred)[1024 + tid * 2];
            float b2 = sred[256 + tid * 2];
            float L  = sred[512 + tid * 2];
            float T  = sred[768 + tid * 2];
            online_merge(b1, i1, b2, L, T,
                         sred[tid * 2 + 1], ((int*)sred)[1024 + tid * 2 + 1],
                         sred[256 + tid * 2 + 1], sred[512 + tid * 2 + 1], sred[768 + tid * 2 + 1]);
            int grow = rowBase + tid;
            P[0 * PF + slice * N_ROWS + grow] = b1;
            P[1 * PF + slice * N_ROWS + grow] = b2;
            P[2 * PF + slice * N_ROWS + grow] = L;
            P[3 * PF + slice * N_ROWS + grow] = T;
            ((int*)P)[4 * PF + slice * N_ROWS + grow] = i1;
        }
    } else {
        __syncthreads();
        atomicAdd(&ws[WS_AVGP + slice * SLICE_K + tid], sred[tid]);
        atomicAdd(&ws[WS_AVGP + slice * SLICE_K + tid + 512], sred[tid + 512]);
    }
}

// merge 8 slice-partials per row -> final stats + flags (row | slicemask<<20) + entropy sum
__global__ void merge_k(const float* __restrict__ P, float* __restrict__ ws,
                        unsigned long long* __restrict__ enc) {
    const int tid = threadIdx.x, lane = tid & 63;
    const int row = blockIdx.x * 256 + tid;
    float b1 = 1e30f, b2 = 1e30f, L = 0.f, T = 0.f; int i1 = 0;
    float sb1[NSLICE];
    #pragma unroll
    for (int s = 0; s < NSLICE; ++s) {
        float nb1 = P[0 * PF + s * N_ROWS + row];
        float nb2 = P[1 * PF + s * N_ROWS + row];
        float nl  = P[2 * PF + s * N_ROWS + row];
        float nT  = P[3 * PF + s * N_ROWS + row];
        int   ni  = ((const int*)P)[4 * PF + s * N_ROWS + row];
        sb1[s] = nb1;
        online_merge(b1, i1, b2, L, T, nb1, ni, nb2, nl, nT);
    }
    ws[WS_BD + row] = b1;
    ((int*)ws)[WS_BI + row] = i1;
    ws[WS_L + row] = L;
    if (b2 - b1 < TAU) {
        uint mask = 0;
        #pragma unroll
        for (int s = 0; s < NSLICE; ++s)
            if (sb1[s] <= b1 + EPS2) mask |= (1u << s);
        int p = atomicAdd(((int*)ws) + WS_FLAGN, 1);
        ((uint*)ws)[WS_FLAGL + p] = (uint)row | (mask << 20);
        enc[p] = ~0ULL;
    }
    float sval = T / L - __logf(L);
    #pragma unroll
    for (int off = 32; off >= 1; off >>= 1) sval += __shfl_xor(sval, off);
    if (lane == 0) atomicAdd(&ws[WS_SCAL + 1], sval);
}

// exact f32 argmin with slice pruning: only slices in the flag's mask are swept.
// 16-lane groups: 4 codes per wave-iter; x-row in registers; no barriers in row loop.
__global__ __launch_bounds__(256) void fixup_k(const float* __restrict__ x,
                                               const float* __restrict__ cb,
                                               float* __restrict__ ws,
                                               unsigned long long* __restrict__ enc) {
    __shared__ __align__(16) float c2sl[SLICE_K];
    const int tid = threadIdx.x, lane = tid & 63, wid = tid >> 6;
    const int g = lane >> 4, l15 = lane & 15;
    const int slice = blockIdx.x & 7;
    for (int i = tid; i < SLICE_K; i += 256) c2sl[i] = ws[WS_C2 + slice * SLICE_K + i];
    __syncthreads();
    const int nf = ((const int*)ws)[WS_FLAGN];
    const int cbase = slice * SLICE_K + wid * 256;     // this wave's 256-code range
    for (int fi = blockIdx.x >> 3; fi < nf; fi += (gridDim.x >> 3)) {
        const uint entry = ((const uint*)ws)[WS_FLAGL + fi];
        if (!((entry >> 20) & (1u << slice))) continue;   // slice can't hold the winner
        const int row = (int)(entry & 0xFFFFFu);
        const float4* xp = (const float4*)(x + (size_t)row * DIM) + l15 * 4;
        float4 xr0 = xp[0], xr1 = xp[1], xr2 = xp[2], xr3 = xp[3];
        const float x2r = ws[WS_X2 + row];
        unsigned long long best = ~0ULL;
        #pragma unroll 4
        for (int j = 0; j < 64; ++j) {
            const int c = cbase + j * 4 + g;
            const float4* cp = (const float4*)(cb + (size_t)c * DIM) + l15 * 4;
            float4 c0 = cp[0], c1 = cp[1], c2 = cp[2], c3 = cp[3];
            float dot = c0.x * xr0.x;
            dot = fmaf(c0.y, xr0.y, dot); dot = fmaf(c0.z, xr0.z, dot); dot = fmaf(c0.w, xr0.w, dot);
            dot = fmaf(c1.x, xr1.x, dot); dot = fmaf(c1.y, xr1.y, dot);
            dot = fmaf(c1.z, xr1.z, dot); dot = fmaf(c1.w, xr1.w, dot);
            dot = fmaf(c2.x, xr2.x, dot); dot = fmaf(c2.y, xr2.y, dot);
            dot = fmaf(c2.z, xr2.z, dot); dot = fmaf(c2.w, xr2.w, dot);
            dot = fmaf(c3.x, xr3.x, dot); dot = fmaf(c3.y, xr3.y, dot);
            dot = fmaf(c3.z, xr3.z, dot); dot = fmaf(c3.w, xr3.w, dot);
            dot += __shfl_xor(dot, 1); dot += __shfl_xor(dot, 2);
            dot += __shfl_xor(dot, 4); dot += __shfl_xor(dot, 8);
            float d2 = fmaxf(fmaf(-2.f, dot, x2r + c2sl[wid * 256 + j * 4 + g]), 0.f);
            float dv = sqrtf(d2);
            unsigned long long e = (((unsigned long long)__float_as_uint(dv)) << 32)
                                 | (unsigned int)c;
            best = (e < best) ? e : best;
        }
        {
            unsigned long long o = __shfl_xor(best, 16);
            best = (o < best) ? o : best;
            o = __shfl_xor(best, 32);
            best = (o < best) ? o : best;
        }
        if (lane == 0) atomicMin(&enc[fi], best);
    }
}

__global__ void unpack_k(const unsigned long long* __restrict__ enc, float* __restrict__ ws) {
    int f = blockIdx.x * 256 + threadIdx.x;
    int nf = ((const int*)ws)[WS_FLAGN];
    if (f < nf) {
        int row = (int)(((const uint*)ws)[WS_FLAGL + f] & 0xFFFFFu);
        ((int*)ws)[WS_BI + row] = (int)(enc[f] & 0xFFFFFFFFu);
    }
}

__global__ void gather_k(const float* __restrict__ x, const float* __restrict__ cb,
                         float* __restrict__ ws, float* __restrict__ outQ,
                         float* __restrict__ outNcbe, float* __restrict__ outIdxF) {
    __shared__ float red2[4];
    const int tid = threadIdx.x, w = tid >> 6, lane = tid & 63;
    float msum = 0.f;
    for (int it = 0; it < 8; ++it) {
        int n = blockIdx.x * 32 + it * 4 + w;
        int idx = ((const int*)ws)[WS_BI + n];
        float4 xv = ((const float4*)(x + (size_t)n * DIM))[lane];
        float4 cv = ((const float4*)(cb + (size_t)idx * DIM))[lane];
        ((float4*)(outQ + (size_t)n * DIM))[lane] = cv;
        float* dst = outNcbe + (size_t)idx * DIM + lane * 4;
        const float g = 0.01f;
        atomicAdd(dst + 0, g * xv.x); atomicAdd(dst + 1, g * xv.y);
        atomicAdd(dst + 2, g * xv.z); atomicAdd(dst + 3, g * xv.w);
        float dx = cv.x - xv.x, dy = cv.y - xv.y, dz = cv.z - xv.z, dw = cv.w - xv.w;
        float s = dx*dx + dy*dy + dz*dz + dw*dw;
        #pragma unroll
        for (int off = 32; off >= 1; off >>= 1) s += __shfl_xor(s, off);
        if (lane == 0) {
            msum += s;
            atomicAdd(&ws[WS_CNT + idx], 1.0f);
            outIdxF[n] = (float)idx;
        }
    }
    if (lane == 0) red2[w] = msum;
    __syncthreads();
    if (tid == 0) atomicAdd(&ws[WS_SCAL + 0], red2[0] + red2[1] + red2[2] + red2[3]);
}

__global__ void stats_k(const float* __restrict__ cse, float* __restrict__ ws,
                        float* __restrict__ outNcse) {
    int tid = threadIdx.x, lane = tid & 63;
    int k = blockIdx.x * 256 + tid;
    float cnt = ws[WS_CNT + k];
    float ncse = 0.99f * cse[k] + 0.01f * cnt;
    outNcse[k] = ncse;
    float ap  = ws[WS_AVGP + k] * (1.0f / N_ROWS);
    float ae  = -(ap * __logf(ap + 1e-5f));
    float app = cnt * (1.0f / N_ROWS);
    float pe  = -(app * __logf(app + 1e-10f));
    #pragma unroll
    for (int off = 32; off >= 1; off >>= 1) {
        ncse += __shfl_xor(ncse, off);
        ae   += __shfl_xor(ae, off);
        pe   += __shfl_xor(pe, off);
    }
    if (lane == 0) {
        atomicAdd(&ws[WS_SCAL + 4], ncse);
        atomicAdd(&ws[WS_SCAL + 2], ae);
        atomicAdd(&ws[WS_SCAL + 3], pe);
    }
}

__global__ void newcb_k(const float* __restrict__ ws, const float* __restrict__ outNcse,
                        const float* __restrict__ outNcbe, float* __restrict__ outNc) {
    int w = threadIdx.x >> 6, lane = threadIdx.x & 63;
    int k = blockIdx.x * 4 + w;
    float n = ws[WS_SCAL + 4];
    float ncse = outNcse[k];
    float smoothed = (ncse + 1e-5f) / (n + (float)KCODES * 1e-5f) * n;
    float inv = 1.0f / smoothed;
    float4 v = ((const float4*)(outNcbe + (size_t)k * DIM))[lane];
    v.x *= inv; v.y *= inv; v.z *= inv; v.w *= inv;
    ((float4*)(outNc + (size_t)k * DIM))[lane] = v;
}

__global__ void finalize_k(const float* __restrict__ ws, float* __restrict__ outLoss,
                           float* __restrict__ outPerp) {
    float mse  = ws[WS_SCAL + 0] * (1.0f / ((float)N_ROWS * 256.0f));
    float sent = -ws[WS_SCAL + 1] * (1.0f / (float)N_ROWS);
    float ent  = sent - ws[WS_SCAL + 2];
    outLoss[0] = 1.25f * mse + 0.1f * ent;
    outPerp[0] = expf(ws[WS_SCAL + 3]);
}

extern "C" void kernel_launch(void* const* d_in, const int* in_sizes, int n_in,
                              void* d_out, int out_size, void* d_ws, size_t ws_size,
                              hipStream_t stream) {
    const float* x   = (const float*)d_in[0];
    const float* cb  = (const float*)d_in[1];
    const float* cse = (const float*)d_in[2];
    const float* cbe = (const float*)d_in[3];
    float* out = (float*)d_out;
    float* ws  = (float*)d_ws;

    float* outQ    = out;
    float* outLoss = out + 8388608;
    float* outPerp = out + 8388609;
    float* outIdxF = out + 8388610;
    float* outNc   = out + 8421378;
    float* outNcse = out + 10518530;
    float* outNcbe = out + 10526722;

    // scratch inside d_out: x f16 in outQ, cb f16 in outNc(+2 align), partials+enc in outNcbe
    ushort* xf = (ushort*)outQ;                    // 16 MB
    ushort* cf = (ushort*)(out + 8421380);         // 4 MB
    float*  P  = outNcbe;                          // 5.24 MB
    unsigned long long* enc = (unsigned long long*)(outNcbe + 5 * PF);  // 256 KB

    (void)hipMemsetAsync(ws + WS_AVGP, 0, (size_t)(WS_FLAGN + 1 - WS_AVGP) * sizeof(float), stream);
    split_k<<<N_ROWS * DIM / 2048, 256, 0, stream>>>(x, xf, ws + WS_X2);
    split_k<<<KCODES * DIM / 2048, 256, 0, stream>>>(cb, cf, ws + WS_C2);
    vq_mfma<1><<<NSLICE * (N_ROWS / BM), 512, 0, stream>>>(xf, cf, ws, P);
    merge_k<<<N_ROWS / 256, 256, 0, stream>>>(P, ws, enc);
    vq_mfma<2><<<NSLICE * (N_ROWS / BM), 512, 0, stream>>>(xf, cf, ws, P);
    fixup_k<<<2048, 256, 0, stream>>>(x, cb, ws, enc);
    unpack_k<<<N_ROWS / 256, 256, 0, stream>>>(enc, ws);
    init_ncbe_k<<<2048, 256, 0, stream>>>(cbe, outNcbe);
    gather_k<<<1024, 256, 0, stream>>>(x, cb, ws, outQ, outNcbe, outIdxF);
    stats_k<<<KCODES / 256, 256, 0, stream>>>(cse, ws, outNcse);
    newcb_k<<<KCODES / 4, 256, 0, stream>>>(ws, outNcse, outNcbe, outNc);
    finalize_k<<<1, 1, 0, stream>>>(ws, outLoss, outPerp);
}